// Round 5
// baseline (524.388 us; speedup 1.0000x reference)
//
#include <hip/hip_runtime.h>

#define D_     784
#define ROWS   4
#define NCLS   10
#define NCLSP  11               // padded part4 stride (float4s) to spread banks
#define BLOCK  512              // 8 waves; packs 2,2,2,2 per SIMD; 4 blocks/CU = 32 waves
#define NB     (65536 / ROWS)   // 16384 blocks
#define TAIL   (D_ - BLOCK)     // 272 tail features handled by threads 0..271

// tanh-approx GELU (|err| vs exact erf-GELU ~5e-4)
__device__ __forceinline__ float gelu_f(float x) {
    float x2    = x * x;
    float inner = fmaf(0.044715f * x, x2, x);
    float e     = exp2f(2.3022082f * inner);          // 2*sqrt(2/pi)*log2(e)
    float r     = __builtin_amdgcn_rcpf(e + 1.0f);
    return fmaf(-x, r, x);                            // x*e/(e+1)
}

__device__ __forceinline__ float4 gelu4(const float4& a) {
    return make_float4(gelu_f(a.x), gelu_f(a.y), gelu_f(a.z), gelu_f(a.w));
}

__device__ __forceinline__ void fma4(float4& a, const float4& h4, float wk) {
    a.x = fmaf(h4.x, wk, a.x);
    a.y = fmaf(h4.y, wk, a.y);
    a.z = fmaf(h4.z, wk, a.z);
    a.w = fmaf(h4.w, wk, a.w);
}

template <int K>
__device__ __forceinline__ void loadIdxW(const int* __restrict__ idx,
                                         const float* __restrict__ w,
                                         int n, int* jc, float* wc) {
    if constexpr (K == 2) {
        int2   j = *(const int2*)(idx + n * 2);
        float2 v = *(const float2*)(w + n * 2);
        jc[0] = j.x; jc[1] = j.y; wc[0] = v.x; wc[1] = v.y;
    } else if constexpr (K == 4) {
        int4   j = *(const int4*)(idx + n * 4);
        float4 v = *(const float4*)(w + n * 4);
        jc[0] = j.x; jc[1] = j.y; jc[2] = j.z; jc[3] = j.w;
        wc[0] = v.x; wc[1] = v.y; wc[2] = v.z; wc[3] = v.w;
    } else {
        int4   ja = *(const int4*)(idx + n * 8);
        int4   jb = *(const int4*)(idx + n * 8 + 4);
        float4 va = *(const float4*)(w + n * 8);
        float4 vb = *(const float4*)(w + n * 8 + 4);
        jc[0] = ja.x; jc[1] = ja.y; jc[2] = ja.z; jc[3] = ja.w;
        jc[4] = jb.x; jc[5] = jb.y; jc[6] = jb.z; jc[7] = jb.w;
        wc[0] = va.x; wc[1] = va.y; wc[2] = va.z; wc[3] = va.w;
        wc[4] = vb.x; wc[5] = vb.y; wc[6] = vb.z; wc[7] = vb.w;
    }
}

// One feature n, 4 rows (one float4). Flat, fully unrolled.
template <int K>
__device__ __forceinline__ void layer_one(const float* __restrict__ src,
                                          float* __restrict__ dst,
                                          const int* __restrict__ idx,
                                          const float* __restrict__ w,
                                          const float* __restrict__ bias,
                                          int n) {
    int   jc[K];
    float wc[K];
    loadIdxW<K>(idx, w, n, jc, wc);
    float  bc = bias[n];
    float4 a  = make_float4(bc, bc, bc, bc);
#pragma unroll
    for (int k = 0; k < K; ++k) {
        float4 g = *(const float4*)(src + jc[k] * 4);
        fma4(a, g, wc[k]);
    }
    *(float4*)(dst + n * 4) = gelu4(a);
}

__global__ __launch_bounds__(BLOCK)
void circnn_kernel(const float* __restrict__ x,
                   const int* __restrict__ idx1, const float* __restrict__ w1, const float* __restrict__ b1,
                   const int* __restrict__ idx2, const float* __restrict__ w2, const float* __restrict__ b2,
                   const int* __restrict__ idx3, const float* __restrict__ w3, const float* __restrict__ b3,
                   const float* __restrict__ fcw, const float* __restrict__ fcb,
                   float* __restrict__ out) {
    __shared__ __align__(16) float bufA[D_ * ROWS];   // 12,544 B: x, h2; then FC partials
    __shared__ __align__(16) float bufB[D_ * ROWS];   // 12,544 B: h1, h3
    __shared__ float logits[ROWS * NCLS];             // 160 B

    const int tid  = threadIdx.x;
    const int row0 = blockIdx.x * ROWS;

    // ---- Stage x -> bufA: 4 strided-coalesced b32 reads -> one b128 write
    const float* xb = x + (size_t)row0 * D_;
    {
        int n = tid;                      // n < 512 < 784, always valid
        float4 v;
        v.x = xb[0 * D_ + n]; v.y = xb[1 * D_ + n];
        v.z = xb[2 * D_ + n]; v.w = xb[3 * D_ + n];
        *(float4*)(bufA + n * 4) = v;
    }
    if (tid < TAIL) {
        int n = BLOCK + tid;
        float4 v;
        v.x = xb[0 * D_ + n]; v.y = xb[1 * D_ + n];
        v.z = xb[2 * D_ + n]; v.w = xb[3 * D_ + n];
        *(float4*)(bufA + n * 4) = v;
    }
    __syncthreads();

    // ---- Three sparse layers, ping-pong A->B->A->B, one barrier each
    layer_one<2>(bufA, bufB, idx1, w1, b1, tid);
    if (tid < TAIL) layer_one<2>(bufA, bufB, idx1, w1, b1, BLOCK + tid);
    __syncthreads();

    layer_one<4>(bufB, bufA, idx2, w2, b2, tid);
    if (tid < TAIL) layer_one<4>(bufB, bufA, idx2, w2, b2, BLOCK + tid);
    __syncthreads();

    layer_one<8>(bufA, bufB, idx3, w3, b3, tid);
    if (tid < TAIL) layer_one<8>(bufA, bufB, idx3, w3, b3, BLOCK + tid);
    __syncthreads();

    // ---- FC phase A: 256 threads (4 waves). tid = jj*4 + p:
    //   p  = low 2 bits -> 4-way split of the 13 n-chunks
    //   jj = bits 2..7  -> feature within chunk (0..63)
    // Quad reduce via __shfl_xor on NAMED members only (no pointer casts ->
    // facc stays in registers; round-1's spill came from the (float*) cast).
    float4* part4 = (float4*)bufA;        // layout [jj*NCLSP + c], 11,264 B (bufA free)
    if (tid < 256) {
        const int p  = tid & 3;
        const int jj = tid >> 2;
        float4 facc[NCLS];
#pragma unroll
        for (int c = 0; c < NCLS; ++c) facc[c] = make_float4(0.f, 0.f, 0.f, 0.f);
#pragma unroll 1
        for (int i = p; i < 13; i += 4) {
            int n = jj + (i << 6);
            if (n < D_) {
                float4 hv = *(const float4*)(bufB + n * 4);   // 4-lane broadcast, conflict-free
#pragma unroll
                for (int c = 0; c < NCLS; ++c)
                    fma4(facc[c], hv, fcw[c * D_ + n]);
            }
        }
#pragma unroll
        for (int c = 0; c < NCLS; ++c) {
            facc[c].x += __shfl_xor(facc[c].x, 1);
            facc[c].y += __shfl_xor(facc[c].y, 1);
            facc[c].z += __shfl_xor(facc[c].z, 1);
            facc[c].w += __shfl_xor(facc[c].w, 1);
            facc[c].x += __shfl_xor(facc[c].x, 2);
            facc[c].y += __shfl_xor(facc[c].y, 2);
            facc[c].z += __shfl_xor(facc[c].z, 2);
            facc[c].w += __shfl_xor(facc[c].w, 2);
        }
        if (p == 0) {
#pragma unroll
            for (int c = 0; c < NCLS; ++c)
                part4[jj * NCLSP + c] = facc[c];
        }
    }
    __syncthreads();

    // ---- FC phase B: 40 threads (r, c) sum 64 jj-partials -> logits
    if (tid < ROWS * NCLS) {
        int r = tid / NCLS, c = tid - r * NCLS;
        const float* pf = (const float*)part4;
        float s = fcb[c];
#pragma unroll 4
        for (int jj = 0; jj < 64; ++jj)
            s += pf[(jj * NCLSP + c) * 4 + r];
        logits[tid] = s;
    }
    __syncthreads();

    // ---- softmax (redundant per-(r,c) thread), coalesced 40-float store
    if (tid < ROWS * NCLS) {
        int r = tid / NCLS;
        const float* lg = logits + r * NCLS;
        float m = lg[0];
#pragma unroll
        for (int c = 1; c < NCLS; ++c) m = fmaxf(m, lg[c]);
        float s = 0.f;
#pragma unroll
        for (int c = 0; c < NCLS; ++c) s += __expf(lg[c] - m);
        out[(size_t)row0 * NCLS + tid] = __expf(logits[tid] - m) / s;
    }
}

extern "C" void kernel_launch(void* const* d_in, const int* in_sizes, int n_in,
                              void* d_out, int out_size, void* d_ws, size_t ws_size,
                              hipStream_t stream) {
    const float* x    = (const float*)d_in[0];
    const int*   idx1 = (const int*)d_in[1];
    const float* w1   = (const float*)d_in[2];
    const float* b1   = (const float*)d_in[3];
    const int*   idx2 = (const int*)d_in[4];
    const float* w2   = (const float*)d_in[5];
    const float* b2   = (const float*)d_in[6];
    const int*   idx3 = (const int*)d_in[7];
    const float* w3   = (const float*)d_in[8];
    const float* b3   = (const float*)d_in[9];
    const float* fcw  = (const float*)d_in[10];
    const float* fcb  = (const float*)d_in[11];
    float* out = (float*)d_out;

    circnn_kernel<<<dim3(NB), dim3(BLOCK), 0, stream>>>(
        x, idx1, w1, b1, idx2, w2, b2, idx3, w3, b3, fcw, fcb, out);
}